// Round 7
// baseline (217.712 us; speedup 1.0000x reference)
//
#include <hip/hip_runtime.h>

// Problem constants (fixed by the reference)
#define BB 4
#define T 128           // T1 == T2
#define D 300
#define D4 75           // D/4 float4 chunks
#define NROW 512        // BB*T

// Session findings:
// - hL/hR stream plateaued at 2.42 TB/s = 1 x 128B line/cy/XCD under ALL
//   structural probes (bytes/payload/occupancy/async/L3 all falsified).
// - (R6) NT loads on hL/hR BROKE the plateau: attn 65 -> <45.8us, e2e
//   227.9 -> 215.3. Mechanism confirmed: per-XCD L2 line-ALLOCATION cap;
//   nt bypasses it. Keep NT on all read-once streams forever.
// - (R7, this) post-NT bound hypothesis: per-wave miss depth. VGPR=24
//   holds ~1 j-iter of loads. Restructure pass 1: 4 j-rows per group,
//   8 NT float4 loads issued back-to-back per wave per d-chunk (static
//   register groups, no dynamic indexing). k/q stay cached (reused).
// - (R1,R3) intra-kernel cross-workgroup dataflow fails correctness here.
//   RULE: cross-block dataflow only at dispatch boundaries. 2 dispatches.

typedef float nf4 __attribute__((ext_vector_type(4)));
__device__ __forceinline__ float4 ntload4(const float4* p) {
    nf4 v = __builtin_nontemporal_load((const nf4*)p);
    union { nf4 a; float4 b; } u; u.a = v; return u.b;
}

// ---------------- Kernel A: projections q = x@WQ.T+bQ, k/v = x@WK.T+bK ----
__global__ __launch_bounds__(320) void proj_kernel(
    const float* __restrict__ query, const float* __restrict__ key,
    const float* __restrict__ value,
    const float* __restrict__ WQ, const float* __restrict__ bQ,
    const float* __restrict__ WK, const float* __restrict__ bK,
    float* __restrict__ qkv /* [3][512][300] */)
{
    const int src  = blockIdx.x >> 6;    // 0=q,1=k,2=v
    const int rblk = blockIdx.x & 63;
    const int r0   = rblk * 8;
    const float* in   = (src == 0) ? query : (src == 1 ? key : value);
    const float* W    = (src == 0) ? WQ : WK;
    const float* bias = (src == 0) ? bQ : bK;
    float* out = qkv + src * (NROW * D);

    __shared__ __align__(16) float lds_in[8 * D];   // 9.6 KB
    for (int idx = threadIdx.x; idx < 8 * D; idx += 320)
        lds_in[idx] = in[r0 * D + idx];
    __syncthreads();

    const int t = threadIdx.x;
    if (t < D) {
        float acc[8];
        const float bv = bias[t];
        #pragma unroll
        for (int r = 0; r < 8; ++r) acc[r] = bv;
        const float4* W4 = (const float4*)(W + t * D);
        for (int e4 = 0; e4 < D4; ++e4) {
            const float4 w = W4[e4];
            #pragma unroll
            for (int r = 0; r < 8; ++r) {
                const float4 x = *(const float4*)(&lds_in[r * D + e4 * 4]);
                acc[r] += w.x * x.x + w.y * x.y + w.z * x.z + w.w * x.w;
            }
        }
        #pragma unroll
        for (int r = 0; r < 8; ++r)
            out[(r0 + r) * D + t] = acc[r];
    }
}

// ---------------- Kernel B: fused scores -> double softmax -> output ------
// grid: 512 blocks (one per (b,i) after swizzle), 1024 threads (16 waves).
// Pass 1: per wave, j-groups of 4 -> 8 NT loads in flight back-to-back.
__global__ __launch_bounds__(1024) void attn_kernel(
    const float* __restrict__ hL, const float* __restrict__ hR,
    const float* __restrict__ qkv, float* __restrict__ outp)
{
    // XCD-contiguous swizzle: (bid&7) is the XCD id; contiguous 64-runs.
    const int swz = (blockIdx.x & 7) * 64 + (blockIdx.x >> 3);
    const int b = swz >> 7;
    const int i = swz & 127;

    const float* qp    = qkv + (b * T + i) * D;
    const float* kbase = qkv + NROW * D + b * T * D;
    const float* vbase = qkv + 2 * NROW * D + b * T * D;

    __shared__ __align__(16) float q_lds[D];
    __shared__ float sc[T];
    __shared__ __align__(16) float red[12][D];   // 14.4 KB

    for (int idx = threadIdx.x; idx < D; idx += 1024) q_lds[idx] = qp[idx];
    __syncthreads();

    const int wave = threadIdx.x >> 6;   // 0..15
    const int lane = threadIdx.x & 63;

    // ---- pass 1: scores[j] = sum_d (q_d + hL[i,j,d]) * (k_jd + hR[j,i,d]) ----
    // j coverage per wave: wave + {0,16,32,48} + 64*g, g=0,1.
    const float4* hL4 = (const float4*)(hL + (size_t)(b * T + i) * T * D);
    const float4* hR4 = (const float4*)hR;
    const float4* k4  = (const float4*)kbase;
    const size_t hRstep = (size_t)16 * T * D4;   // j += 16 stride in float4

    #pragma unroll
    for (int g = 0; g < 2; ++g) {
        const int j0 = wave + g * 64;
        float4 A0 = {0.f,0.f,0.f,0.f}, A1 = {0.f,0.f,0.f,0.f};
        float4 A2 = {0.f,0.f,0.f,0.f}, A3 = {0.f,0.f,0.f,0.f};
        #pragma unroll
        for (int it = 0; it < 2; ++it) {
            const int d4 = lane + it * 64;
            if (d4 < D4) {
                const float4 qq = *(const float4*)(&q_lds[d4 * 4]);
                const size_t hRo = ((size_t)(b * T + j0) * T + i) * D4 + d4;
                // 8 NT loads issued back-to-back: the in-flight group.
                const float4 l0 = ntload4(&hL4[(j0     ) * D4 + d4]);
                const float4 l1 = ntload4(&hL4[(j0 + 16) * D4 + d4]);
                const float4 l2 = ntload4(&hL4[(j0 + 32) * D4 + d4]);
                const float4 l3 = ntload4(&hL4[(j0 + 48) * D4 + d4]);
                const float4 r0 = ntload4(&hR4[hRo]);
                const float4 r1 = ntload4(&hR4[hRo + hRstep]);
                const float4 r2 = ntload4(&hR4[hRo + 2 * hRstep]);
                const float4 r3 = ntload4(&hR4[hRo + 3 * hRstep]);
                // cached k rows (L2-shared across the 64 blocks per batch)
                {
                    const float4 kk = k4[(j0     ) * D4 + d4];
                    A0.x += (qq.x + l0.x) * (kk.x + r0.x);
                    A0.y += (qq.y + l0.y) * (kk.y + r0.y);
                    A0.z += (qq.z + l0.z) * (kk.z + r0.z);
                    A0.w += (qq.w + l0.w) * (kk.w + r0.w);
                }
                {
                    const float4 kk = k4[(j0 + 16) * D4 + d4];
                    A1.x += (qq.x + l1.x) * (kk.x + r1.x);
                    A1.y += (qq.y + l1.y) * (kk.y + r1.y);
                    A1.z += (qq.z + l1.z) * (kk.z + r1.z);
                    A1.w += (qq.w + l1.w) * (kk.w + r1.w);
                }
                {
                    const float4 kk = k4[(j0 + 32) * D4 + d4];
                    A2.x += (qq.x + l2.x) * (kk.x + r2.x);
                    A2.y += (qq.y + l2.y) * (kk.y + r2.y);
                    A2.z += (qq.z + l2.z) * (kk.z + r2.z);
                    A2.w += (qq.w + l2.w) * (kk.w + r2.w);
                }
                {
                    const float4 kk = k4[(j0 + 48) * D4 + d4];
                    A3.x += (qq.x + l3.x) * (kk.x + r3.x);
                    A3.y += (qq.y + l3.y) * (kk.y + r3.y);
                    A3.z += (qq.z + l3.z) * (kk.z + r3.z);
                    A3.w += (qq.w + l3.w) * (kk.w + r3.w);
                }
            }
        }
        float s0 = A0.x + A0.y + A0.z + A0.w;
        float s1 = A1.x + A1.y + A1.z + A1.w;
        float s2 = A2.x + A2.y + A2.z + A2.w;
        float s3 = A3.x + A3.y + A3.z + A3.w;
        #pragma unroll
        for (int off = 32; off > 0; off >>= 1) {
            s0 += __shfl_down(s0, off, 64);
            s1 += __shfl_down(s1, off, 64);
            s2 += __shfl_down(s2, off, 64);
            s3 += __shfl_down(s3, off, 64);
        }
        if (lane == 0) {
            sc[j0]      = s0;
            sc[j0 + 16] = s1;
            sc[j0 + 32] = s2;
            sc[j0 + 48] = s3;
        }
    }
    __syncthreads();

    // ---- softmax + sharpening (wave 0 only; 2 scores per lane) ----
    if (wave == 0) {
        float s0 = sc[lane], s1 = sc[lane + 64];
        float m = fmaxf(s0, s1);
        #pragma unroll
        for (int off = 32; off > 0; off >>= 1) m = fmaxf(m, __shfl_xor(m, off, 64));
        float e0 = __expf(s0 - m), e1 = __expf(s1 - m);
        float sum = e0 + e1;
        #pragma unroll
        for (int off = 32; off > 0; off >>= 1) sum += __shfl_xor(sum, off, 64);
        const float inv = 1.0f / sum;
        // sharpen: softmax(1000 * p), clamp to [0,1]
        float t0 = 1000.0f * (e0 * inv), t1 = 1000.0f * (e1 * inv);
        float m2 = fmaxf(t0, t1);
        #pragma unroll
        for (int off = 32; off > 0; off >>= 1) m2 = fmaxf(m2, __shfl_xor(m2, off, 64));
        float f0 = __expf(t0 - m2), f1 = __expf(t1 - m2);
        float sum2 = f0 + f1;
        #pragma unroll
        for (int off = 32; off > 0; off >>= 1) sum2 += __shfl_xor(sum2, off, 64);
        const float inv2 = 1.0f / sum2;
        sc[lane]      = fminf(fmaxf(f0 * inv2, 0.f), 1.f);
        sc[lane + 64] = fminf(fmaxf(f1 * inv2, 0.f), 1.f);
    }
    __syncthreads();

    // ---- pass 2: out[d] = sum_j attn_j * (v[j,d] + hR[j,i,d]) ----
    // Sharpened attn is ~one-hot: the 1e-12 skip avoids nearly all loads.
    // Pass-2 loads stay CACHED (survivors are few; NT pass-1 means they
    // come from HBM once — negligible at ~1-2 rows per i).
    const int tid = threadIdx.x;
    if (tid < 12 * D4) {
        const int grp = tid / D4;    // 0..11: j-split
        const int d4  = tid % D4;
        float4 acc = {0.f, 0.f, 0.f, 0.f};
        for (int j = grp; j < T; j += 12) {
            const float aj = sc[j];
            if (aj >= 1e-12f) {      // skip error bound < 1e-9 << 0.104 threshold
                const float4 v4 = *(const float4*)(vbase + j * D + d4 * 4);
                const float4 r4 = *(const float4*)(hR + ((size_t)(b * T + j) * T + i) * D + d4 * 4);
                acc.x += aj * (v4.x + r4.x);
                acc.y += aj * (v4.y + r4.y);
                acc.z += aj * (v4.z + r4.z);
                acc.w += aj * (v4.w + r4.w);
            }
        }
        *(float4*)(&red[grp][d4 * 4]) = acc;
    }
    __syncthreads();
    if (tid < D4) {
        float4 o = {0.f, 0.f, 0.f, 0.f};
        #pragma unroll
        for (int g = 0; g < 12; ++g) {
            const float4 p = *(const float4*)(&red[g][tid * 4]);
            o.x += p.x; o.y += p.y; o.z += p.z; o.w += p.w;
        }
        *(float4*)(outp + (size_t)(b * T + i) * D + tid * 4) = o;
    }
}

extern "C" void kernel_launch(void* const* d_in, const int* in_sizes, int n_in,
                              void* d_out, int out_size, void* d_ws, size_t ws_size,
                              hipStream_t stream) {
    const float* query = (const float*)d_in[0];
    const float* key   = (const float*)d_in[1];
    const float* value = (const float*)d_in[2];
    const float* hL    = (const float*)d_in[3];
    const float* hR    = (const float*)d_in[4];
    const float* WQ    = (const float*)d_in[5];
    const float* bQ    = (const float*)d_in[6];
    const float* WK    = (const float*)d_in[7];
    const float* bK    = (const float*)d_in[8];
    float* out = (float*)d_out;
    float* qkv = (float*)d_ws;   // 3*512*300*4 = 1.84 MB

    proj_kernel<<<dim3(192), dim3(320), 0, stream>>>(query, key, value, WQ, bQ, WK, bK, qkv);
    attn_kernel<<<dim3(512), dim3(1024), 0, stream>>>(hL, hR, qkv, out);
}

// Round 8
// 217.063 us; speedup vs baseline: 1.0030x; 1.0030x over previous
//
#include <hip/hip_runtime.h>

// Problem constants (fixed by the reference)
#define BB 4
#define T 128           // T1 == T2
#define D 300
#define D4 75           // D/4 float4 chunks
#define NROW 512        // BB*T

// Session findings:
// - Cached-path plateau 2.42 TB/s = L2 line-allocation cap (1 line/cy/XCD).
//   Falsified levers: bytes, payload/contiguity, occupancy, async-depth,
//   L3-residency. (R6) NT loads on hL+hR bypass the cap: attn 65->~52us,
//   e2e 227.9->215.3. (R7) explicit 8-deep load groups: attn ~55us (worse;
//   compiler already saturates per-wave MLP) -> reverted.
// - (R8, this) split-path theory: cached path (~2.42 TB/s, idle in R6) and
//   NT path (~3.0-3.5 TB/s) may be parallel limiters. hL (flat stream) ->
//   cached; hR (scattered 1200B granules) -> NT. If parallel: attn ~35-42us.
//   If flat: shared fabric limiter -> roofline.
// - Fixed e2e overhead ~157us (harness: 300MB ws fill 46us + graph/launch).
// - (R1,R3) RULE: cross-block dataflow only at dispatch boundaries.

typedef float nf4 __attribute__((ext_vector_type(4)));
__device__ __forceinline__ float4 ntload4(const float4* p) {
    nf4 v = __builtin_nontemporal_load((const nf4*)p);
    union { nf4 a; float4 b; } u; u.a = v; return u.b;
}

// ---------------- Kernel A: projections q = x@WQ.T+bQ, k/v = x@WK.T+bK ----
__global__ __launch_bounds__(320) void proj_kernel(
    const float* __restrict__ query, const float* __restrict__ key,
    const float* __restrict__ value,
    const float* __restrict__ WQ, const float* __restrict__ bQ,
    const float* __restrict__ WK, const float* __restrict__ bK,
    float* __restrict__ qkv /* [3][512][300] */)
{
    const int src  = blockIdx.x >> 6;    // 0=q,1=k,2=v
    const int rblk = blockIdx.x & 63;
    const int r0   = rblk * 8;
    const float* in   = (src == 0) ? query : (src == 1 ? key : value);
    const float* W    = (src == 0) ? WQ : WK;
    const float* bias = (src == 0) ? bQ : bK;
    float* out = qkv + src * (NROW * D);

    __shared__ __align__(16) float lds_in[8 * D];   // 9.6 KB
    for (int idx = threadIdx.x; idx < 8 * D; idx += 320)
        lds_in[idx] = in[r0 * D + idx];
    __syncthreads();

    const int t = threadIdx.x;
    if (t < D) {
        float acc[8];
        const float bv = bias[t];
        #pragma unroll
        for (int r = 0; r < 8; ++r) acc[r] = bv;
        const float4* W4 = (const float4*)(W + t * D);
        for (int e4 = 0; e4 < D4; ++e4) {
            const float4 w = W4[e4];
            #pragma unroll
            for (int r = 0; r < 8; ++r) {
                const float4 x = *(const float4*)(&lds_in[r * D + e4 * 4]);
                acc[r] += w.x * x.x + w.y * x.y + w.z * x.z + w.w * x.w;
            }
        }
        #pragma unroll
        for (int r = 0; r < 8; ++r)
            out[(r0 + r) * D + t] = acc[r];
    }
}

// ---------------- Kernel B: fused scores -> double softmax -> output ------
// grid: 512 blocks (one per (b,i) after swizzle), 1024 threads (16 waves).
// R6 structure; hL CACHED (L2-alloc path), hR NT (bypass path).
__global__ __launch_bounds__(1024) void attn_kernel(
    const float* __restrict__ hL, const float* __restrict__ hR,
    const float* __restrict__ qkv, float* __restrict__ outp)
{
    // XCD-contiguous swizzle: (bid&7) is the XCD id; contiguous 64-runs.
    const int swz = (blockIdx.x & 7) * 64 + (blockIdx.x >> 3);
    const int b = swz >> 7;
    const int i = swz & 127;

    const float* qp    = qkv + (b * T + i) * D;
    const float* kbase = qkv + NROW * D + b * T * D;
    const float* vbase = qkv + 2 * NROW * D + b * T * D;

    __shared__ __align__(16) float q_lds[D];
    __shared__ float sc[T];
    __shared__ __align__(16) float red[12][D];   // 14.4 KB

    for (int idx = threadIdx.x; idx < D; idx += 1024) q_lds[idx] = qp[idx];
    __syncthreads();

    const int wave = threadIdx.x >> 6;   // 0..15
    const int lane = threadIdx.x & 63;

    // ---- pass 1: scores[j] = sum_d (q_d + hL[i,j,d]) * (k_jd + hR[j,i,d]) ----
    const float4* hL4 = (const float4*)(hL + (size_t)(b * T + i) * T * D);
    for (int j = wave; j < T; j += 16) {       // 8 iterations per wave
        const float4* hRrow = (const float4*)(hR + ((size_t)(b * T + j) * T + i) * D);
        const float4* krow  = (const float4*)(kbase + j * D);
        float4 a = {0.f, 0.f, 0.f, 0.f};
        #pragma unroll
        for (int it = 0; it < 2; ++it) {
            const int d4 = lane + it * 64;
            if (d4 < D4) {
                const float4 l  = hL4[j * D4 + d4];     // CACHED: L2-alloc path
                const float4 r  = ntload4(&hRrow[d4]);  // NT: bypass path
                const float4 kk = krow[d4];
                const float4 qq = *(const float4*)(&q_lds[d4 * 4]);
                a.x += (qq.x + l.x) * (kk.x + r.x);
                a.y += (qq.y + l.y) * (kk.y + r.y);
                a.z += (qq.z + l.z) * (kk.z + r.z);
                a.w += (qq.w + l.w) * (kk.w + r.w);
            }
        }
        float s = a.x + a.y + a.z + a.w;
        #pragma unroll
        for (int off = 32; off > 0; off >>= 1)
            s += __shfl_down(s, off, 64);
        if (lane == 0) sc[j] = s;
    }
    __syncthreads();

    // ---- softmax + sharpening (wave 0 only; 2 scores per lane) ----
    if (wave == 0) {
        float s0 = sc[lane], s1 = sc[lane + 64];
        float m = fmaxf(s0, s1);
        #pragma unroll
        for (int off = 32; off > 0; off >>= 1) m = fmaxf(m, __shfl_xor(m, off, 64));
        float e0 = __expf(s0 - m), e1 = __expf(s1 - m);
        float sum = e0 + e1;
        #pragma unroll
        for (int off = 32; off > 0; off >>= 1) sum += __shfl_xor(sum, off, 64);
        const float inv = 1.0f / sum;
        // sharpen: softmax(1000 * p), clamp to [0,1]
        float t0 = 1000.0f * (e0 * inv), t1 = 1000.0f * (e1 * inv);
        float m2 = fmaxf(t0, t1);
        #pragma unroll
        for (int off = 32; off > 0; off >>= 1) m2 = fmaxf(m2, __shfl_xor(m2, off, 64));
        float f0 = __expf(t0 - m2), f1 = __expf(t1 - m2);
        float sum2 = f0 + f1;
        #pragma unroll
        for (int off = 32; off > 0; off >>= 1) sum2 += __shfl_xor(sum2, off, 64);
        const float inv2 = 1.0f / sum2;
        sc[lane]      = fminf(fmaxf(f0 * inv2, 0.f), 1.f);
        sc[lane + 64] = fminf(fmaxf(f1 * inv2, 0.f), 1.f);
    }
    __syncthreads();

    // ---- pass 2: out[d] = sum_j attn_j * (v[j,d] + hR[j,i,d]) ----
    // Sharpened attn is ~one-hot: the 1e-12 skip avoids nearly all loads.
    const int tid = threadIdx.x;
    if (tid < 12 * D4) {
        const int grp = tid / D4;    // 0..11: j-split
        const int d4  = tid % D4;
        float4 acc = {0.f, 0.f, 0.f, 0.f};
        for (int j = grp; j < T; j += 12) {
            const float aj = sc[j];
            if (aj >= 1e-12f) {      // skip error bound < 1e-9 << 0.104 threshold
                const float4 v4 = *(const float4*)(vbase + j * D + d4 * 4);
                const float4 r4 = *(const float4*)(hR + ((size_t)(b * T + j) * T + i) * D + d4 * 4);
                acc.x += aj * (v4.x + r4.x);
                acc.y += aj * (v4.y + r4.y);
                acc.z += aj * (v4.z + r4.z);
                acc.w += aj * (v4.w + r4.w);
            }
        }
        *(float4*)(&red[grp][d4 * 4]) = acc;
    }
    __syncthreads();
    if (tid < D4) {
        float4 o = {0.f, 0.f, 0.f, 0.f};
        #pragma unroll
        for (int g = 0; g < 12; ++g) {
            const float4 p = *(const float4*)(&red[g][tid * 4]);
            o.x += p.x; o.y += p.y; o.z += p.z; o.w += p.w;
        }
        *(float4*)(outp + (size_t)(b * T + i) * D + tid * 4) = o;
    }
}

extern "C" void kernel_launch(void* const* d_in, const int* in_sizes, int n_in,
                              void* d_out, int out_size, void* d_ws, size_t ws_size,
                              hipStream_t stream) {
    const float* query = (const float*)d_in[0];
    const float* key   = (const float*)d_in[1];
    const float* value = (const float*)d_in[2];
    const float* hL    = (const float*)d_in[3];
    const float* hR    = (const float*)d_in[4];
    const float* WQ    = (const float*)d_in[5];
    const float* bQ    = (const float*)d_in[6];
    const float* WK    = (const float*)d_in[7];
    const float* bK    = (const float*)d_in[8];
    float* out = (float*)d_out;
    float* qkv = (float*)d_ws;   // 3*512*300*4 = 1.84 MB

    proj_kernel<<<dim3(192), dim3(320), 0, stream>>>(query, key, value, WQ, bQ, WK, bK, qkv);
    attn_kernel<<<dim3(512), dim3(1024), 0, stream>>>(hL, hR, qkv, out);
}

// Round 9
// 214.520 us; speedup vs baseline: 1.0149x; 1.0119x over previous
//
#include <hip/hip_runtime.h>

// Problem constants (fixed by the reference)
#define BB 4
#define T 128           // T1 == T2
#define D 300
#define D4 75           // D/4 float4 chunks
#define NROW 512        // BB*T

// Session findings (final state):
// - Cached-path plateau 2.42 TB/s = per-XCD L2 line-allocation cap.
//   Falsified levers: bytes (R2), payload/contiguity (R5), occupancy
//   (R4 11% vs 40-79% flat), per-wave load depth (R7), split cached/NT
//   paths (R8), async/reg-pipelines + L3-residency (prev session).
// - (R6) NT loads on BOTH hL and hR bypass the L2-alloc cap: attn 65->~52us,
//   e2e 227.9 -> 215.3 (session best). This file restores R6 exactly.
// - Post-NT read rate ~3.0 TB/s == m13 copy's read side (3.15 TB/s);
//   pure-write fill does 6.7 TB/s but no gfx950 datapoint shows pure-read
//   above ~3.15 -> treat as the read ceiling. 157MB/3.1TB/s ~= 50us floor.
// - bf16-truncated hL/hR reads rejected: x1000 sharpening = argmax select;
//   score err ~0.19 vs top-2 gaps -> ~2% rows flip vs fp32 ref -> fail.
// - (R1,R3) RULE: cross-block dataflow only at dispatch boundaries.
//   2 dispatches; each extra dispatch costs ~11us e2e.

typedef float nf4 __attribute__((ext_vector_type(4)));
__device__ __forceinline__ float4 ntload4(const float4* p) {
    nf4 v = __builtin_nontemporal_load((const nf4*)p);
    union { nf4 a; float4 b; } u; u.a = v; return u.b;
}

// ---------------- Kernel A: projections q = x@WQ.T+bQ, k/v = x@WK.T+bK ----
__global__ __launch_bounds__(320) void proj_kernel(
    const float* __restrict__ query, const float* __restrict__ key,
    const float* __restrict__ value,
    const float* __restrict__ WQ, const float* __restrict__ bQ,
    const float* __restrict__ WK, const float* __restrict__ bK,
    float* __restrict__ qkv /* [3][512][300] */)
{
    const int src  = blockIdx.x >> 6;    // 0=q,1=k,2=v
    const int rblk = blockIdx.x & 63;
    const int r0   = rblk * 8;
    const float* in   = (src == 0) ? query : (src == 1 ? key : value);
    const float* W    = (src == 0) ? WQ : WK;
    const float* bias = (src == 0) ? bQ : bK;
    float* out = qkv + src * (NROW * D);

    __shared__ __align__(16) float lds_in[8 * D];   // 9.6 KB
    for (int idx = threadIdx.x; idx < 8 * D; idx += 320)
        lds_in[idx] = in[r0 * D + idx];
    __syncthreads();

    const int t = threadIdx.x;
    if (t < D) {
        float acc[8];
        const float bv = bias[t];
        #pragma unroll
        for (int r = 0; r < 8; ++r) acc[r] = bv;
        const float4* W4 = (const float4*)(W + t * D);
        for (int e4 = 0; e4 < D4; ++e4) {
            const float4 w = W4[e4];
            #pragma unroll
            for (int r = 0; r < 8; ++r) {
                const float4 x = *(const float4*)(&lds_in[r * D + e4 * 4]);
                acc[r] += w.x * x.x + w.y * x.y + w.z * x.z + w.w * x.w;
            }
        }
        #pragma unroll
        for (int r = 0; r < 8; ++r)
            out[(r0 + r) * D + t] = acc[r];
    }
}

// ---------------- Kernel B: fused scores -> double softmax -> output ------
// grid: 512 blocks (one per (b,i) after swizzle), 1024 threads (16 waves).
// R6 configuration: NT on both read-once streams (hL and hR).
__global__ __launch_bounds__(1024) void attn_kernel(
    const float* __restrict__ hL, const float* __restrict__ hR,
    const float* __restrict__ qkv, float* __restrict__ outp)
{
    // XCD-contiguous swizzle: (bid&7) is the XCD id; contiguous 64-runs.
    const int swz = (blockIdx.x & 7) * 64 + (blockIdx.x >> 3);
    const int b = swz >> 7;
    const int i = swz & 127;

    const float* qp    = qkv + (b * T + i) * D;
    const float* kbase = qkv + NROW * D + b * T * D;
    const float* vbase = qkv + 2 * NROW * D + b * T * D;

    __shared__ __align__(16) float q_lds[D];
    __shared__ float sc[T];
    __shared__ __align__(16) float red[12][D];   // 14.4 KB

    for (int idx = threadIdx.x; idx < D; idx += 1024) q_lds[idx] = qp[idx];
    __syncthreads();

    const int wave = threadIdx.x >> 6;   // 0..15
    const int lane = threadIdx.x & 63;

    // ---- pass 1: scores[j] = sum_d (q_d + hL[i,j,d]) * (k_jd + hR[j,i,d]) ----
    const float4* hL4 = (const float4*)(hL + (size_t)(b * T + i) * T * D);
    for (int j = wave; j < T; j += 16) {       // 8 iterations per wave
        const float4* hRrow = (const float4*)(hR + ((size_t)(b * T + j) * T + i) * D);
        const float4* krow  = (const float4*)(kbase + j * D);
        float4 a = {0.f, 0.f, 0.f, 0.f};
        #pragma unroll
        for (int it = 0; it < 2; ++it) {
            const int d4 = lane + it * 64;
            if (d4 < D4) {
                const float4 l  = ntload4(&hL4[j * D4 + d4]);   // NT: read-once
                const float4 r  = ntload4(&hRrow[d4]);          // NT: read-once
                const float4 kk = krow[d4];
                const float4 qq = *(const float4*)(&q_lds[d4 * 4]);
                a.x += (qq.x + l.x) * (kk.x + r.x);
                a.y += (qq.y + l.y) * (kk.y + r.y);
                a.z += (qq.z + l.z) * (kk.z + r.z);
                a.w += (qq.w + l.w) * (kk.w + r.w);
            }
        }
        float s = a.x + a.y + a.z + a.w;
        #pragma unroll
        for (int off = 32; off > 0; off >>= 1)
            s += __shfl_down(s, off, 64);
        if (lane == 0) sc[j] = s;
    }
    __syncthreads();

    // ---- softmax + sharpening (wave 0 only; 2 scores per lane) ----
    if (wave == 0) {
        float s0 = sc[lane], s1 = sc[lane + 64];
        float m = fmaxf(s0, s1);
        #pragma unroll
        for (int off = 32; off > 0; off >>= 1) m = fmaxf(m, __shfl_xor(m, off, 64));
        float e0 = __expf(s0 - m), e1 = __expf(s1 - m);
        float sum = e0 + e1;
        #pragma unroll
        for (int off = 32; off > 0; off >>= 1) sum += __shfl_xor(sum, off, 64);
        const float inv = 1.0f / sum;
        // sharpen: softmax(1000 * p), clamp to [0,1]
        float t0 = 1000.0f * (e0 * inv), t1 = 1000.0f * (e1 * inv);
        float m2 = fmaxf(t0, t1);
        #pragma unroll
        for (int off = 32; off > 0; off >>= 1) m2 = fmaxf(m2, __shfl_xor(m2, off, 64));
        float f0 = __expf(t0 - m2), f1 = __expf(t1 - m2);
        float sum2 = f0 + f1;
        #pragma unroll
        for (int off = 32; off > 0; off >>= 1) sum2 += __shfl_xor(sum2, off, 64);
        const float inv2 = 1.0f / sum2;
        sc[lane]      = fminf(fmaxf(f0 * inv2, 0.f), 1.f);
        sc[lane + 64] = fminf(fmaxf(f1 * inv2, 0.f), 1.f);
    }
    __syncthreads();

    // ---- pass 2: out[d] = sum_j attn_j * (v[j,d] + hR[j,i,d]) ----
    // Sharpened attn is ~one-hot: the 1e-12 skip avoids nearly all loads.
    // Pass-2 loads stay CACHED (survivors are few; NT pass-1 means they
    // come from HBM once — negligible at ~1-2 rows per i).
    const int tid = threadIdx.x;
    if (tid < 12 * D4) {
        const int grp = tid / D4;    // 0..11: j-split
        const int d4  = tid % D4;
        float4 acc = {0.f, 0.f, 0.f, 0.f};
        for (int j = grp; j < T; j += 12) {
            const float aj = sc[j];
            if (aj >= 1e-12f) {      // skip error bound < 1e-9 << 0.104 threshold
                const float4 v4 = *(const float4*)(vbase + j * D + d4 * 4);
                const float4 r4 = *(const float4*)(hR + ((size_t)(b * T + j) * T + i) * D + d4 * 4);
                acc.x += aj * (v4.x + r4.x);
                acc.y += aj * (v4.y + r4.y);
                acc.z += aj * (v4.z + r4.z);
                acc.w += aj * (v4.w + r4.w);
            }
        }
        *(float4*)(&red[grp][d4 * 4]) = acc;
    }
    __syncthreads();
    if (tid < D4) {
        float4 o = {0.f, 0.f, 0.f, 0.f};
        #pragma unroll
        for (int g = 0; g < 12; ++g) {
            const float4 p = *(const float4*)(&red[g][tid * 4]);
            o.x += p.x; o.y += p.y; o.z += p.z; o.w += p.w;
        }
        *(float4*)(outp + (size_t)(b * T + i) * D + tid * 4) = o;
    }
}

extern "C" void kernel_launch(void* const* d_in, const int* in_sizes, int n_in,
                              void* d_out, int out_size, void* d_ws, size_t ws_size,
                              hipStream_t stream) {
    const float* query = (const float*)d_in[0];
    const float* key   = (const float*)d_in[1];
    const float* value = (const float*)d_in[2];
    const float* hL    = (const float*)d_in[3];
    const float* hR    = (const float*)d_in[4];
    const float* WQ    = (const float*)d_in[5];
    const float* bQ    = (const float*)d_in[6];
    const float* WK    = (const float*)d_in[7];
    const float* bK    = (const float*)d_in[8];
    float* out = (float*)d_out;
    float* qkv = (float*)d_ws;   // 3*512*300*4 = 1.84 MB

    proj_kernel<<<dim3(192), dim3(320), 0, stream>>>(query, key, value, WQ, bQ, WK, bK, qkv);
    attn_kernel<<<dim3(512), dim3(1024), 0, stream>>>(hL, hR, qkv, out);
}